// Round 7
// baseline (295.569 us; speedup 1.0000x reference)
//
#include <hip/hip_runtime.h>
#include <stdint.h>

#define GSZ 256
#define NV (GSZ*GSZ)
#define NS 2048
#define CELLS (255*255)          // 65025 cells per mesh
#define FH CELLS                 // first-half face count
#define NF (2*CELLS)             // 130050 faces per mesh
#define CH 8                     // chunks per mesh-loss block

// analytic grid-topology counts (verified against reference dedup):
// edges:  horiz 256*255=65280 | vert 255*256=65280 | diag 255*255=65025  -> 195585
// pairs:  horiz 254*255=64770 | vert 255*254=64770 | diag 255*255=65025  -> 194565
#define EH 65280
#define EV 65280
#define PH 64770
#define PV 64770

struct F3 { float x, y, z; };

__device__ __forceinline__ F3 ldv3(const float* __restrict__ p, int idx) {
    const float* q = p + 3*(size_t)idx;
    F3 r; r.x = q[0]; r.y = q[1]; r.z = q[2]; return r;
}
__device__ __forceinline__ F3 f3sub(F3 a, F3 b) { return F3{a.x-b.x, a.y-b.y, a.z-b.z}; }
__device__ __forceinline__ F3 f3cross(F3 a, F3 b) {
    return F3{a.y*b.z - a.z*b.y, a.z*b.x - a.x*b.z, a.x*b.y - a.y*b.x};
}
__device__ __forceinline__ float f3dot(F3 a, F3 b) { return a.x*b.x + a.y*b.y + a.z*b.z; }

__device__ __forceinline__ uint64_t splitmix64(uint64_t& s) {
    s += 0x9E3779B97F4A7C15ULL;
    uint64_t z = s;
    z = (z ^ (z >> 30)) * 0xBF58476D1CE4E5B9ULL;
    z = (z ^ (z >> 27)) * 0x94D049BB133111EBULL;
    return z ^ (z >> 31);
}

// result valid on thread 0 only; blockDim.x == 256
__device__ __forceinline__ float blockReduceSum256(float v) {
    __shared__ float s[4];
    int lane = threadIdx.x & 63, w = threadIdx.x >> 6;
    #pragma unroll
    for (int o = 32; o > 0; o >>= 1) v += __shfl_down(v, o, 64);
    if (lane == 0) s[w] = v;
    __syncthreads();
    if (threadIdx.x == 0) v = s[0] + s[1] + s[2] + s[3];
    return v;
}

// ---------------------------------------------------------------------------
// k_area: per-cell face areas for both clouds + per-block max written to a
// PRIVATE slot (plain store, NOT a same-address atomic: 4065 single-address
// atomicMax RMWs serialized = +42us — round-4 lesson).
// Block 0 also zeroes the ticket counters used by k_heavy (runs before it in
// stream order).
__global__ void k_area(const float* __restrict__ vp, const float* __restrict__ vt,
                       int B, float* __restrict__ areas, float* __restrict__ blockmax,
                       unsigned* __restrict__ ctrl) {
    if (blockIdx.x == 0 && threadIdx.x < 32) ctrl[threadIdx.x] = 0u;
    int gid = blockIdx.x*256 + threadIdx.x;
    int total = 2*B*CELLS;
    float mloc = 0.f;
    if (gid < total) {
        int m = gid / CELLS;              // mesh id (0..2B)
        int c = gid - m*CELLS;            // cell id
        int i = c / 255, j = c - i*255;
        const float* verts = (m < B ? vp + (size_t)m*NV*3
                                    : vt + (size_t)(m-B)*NV*3);
        int b00 = i*GSZ + j;
        F3 v00 = ldv3(verts, b00);
        F3 v01 = ldv3(verts, b00+1);
        F3 v10 = ldv3(verts, b00+GSZ);
        F3 v11 = ldv3(verts, b00+GSZ+1);
        F3 c1 = f3cross(f3sub(v01, v00), f3sub(v10, v00));
        F3 c2 = f3cross(f3sub(v11, v01), f3sub(v10, v01));
        float a1 = 0.5f * sqrtf(f3dot(c1, c1));
        float a2 = 0.5f * sqrtf(f3dot(c2, c2));
        size_t base = (size_t)m*NF;
        areas[base + c]      = a1;   // face f1[c]
        areas[base + FH + c] = a2;   // face f2[c]
        mloc = fmaxf(a1, a2);
    }
    #pragma unroll
    for (int o = 32; o > 0; o >>= 1) mloc = fmaxf(mloc, __shfl_down(mloc, o, 64));
    __shared__ float s[4];
    int lane = threadIdx.x & 63, w = threadIdx.x >> 6;
    if (lane == 0) s[w] = mloc;
    __syncthreads();
    if (threadIdx.x == 0)
        blockmax[blockIdx.x] = fmaxf(fmaxf(s[0], s[1]), fmaxf(s[2], s[3]));
}

// ---------------------------------------------------------------------------
// k_sample: area-weighted rejection sampling, materialized ONCE (regen-in-
// consumer was an 18x redundant gather storm — round-3 lesson). Output is
// float4 with w=|p|^2 for the FMA-form chamfer distance.
// grid: (2*B*NS)/256 = 128 blocks
__global__ void k_sample(const float* __restrict__ vp, const float* __restrict__ vt,
                         int B, const float* __restrict__ areas,
                         const float* __restrict__ blockmax, int nbm,
                         float4* __restrict__ samples) {
    // block-wide reduce of global max area (L2-hot, ~16 coalesced loads/thread)
    float m = 0.f;
    for (int k = threadIdx.x; k < nbm; k += 256) m = fmaxf(m, blockmax[k]);
    #pragma unroll
    for (int o = 32; o > 0; o >>= 1) m = fmaxf(m, __shfl_down(m, o, 64));
    __shared__ float s[4];
    int lane = threadIdx.x & 63, w = threadIdx.x >> 6;
    if (lane == 0) s[w] = m;
    __syncthreads();
    __shared__ float sMaxA;
    if (threadIdx.x == 0) sMaxA = fmaxf(fmaxf(s[0], s[1]), fmaxf(s[2], s[3]));
    __syncthreads();
    float maxA = sMaxA;

    int gid = blockIdx.x*256 + threadIdx.x;       // 0 .. 2*B*NS
    int cloud = gid / (B*NS);
    int rem = gid - cloud*(B*NS);
    int b = rem / NS;
    const float* verts = (cloud ? vt : vp) + (size_t)b*NV*3;
    const float* am = areas + (size_t)(cloud*B + b)*NF;

    uint64_t st = ((uint64_t)(gid + 1) * 0x9E3779B97F4A7C15ULL) ^ 0xC0FFEE123456789ULL;
    int f = 0;
    for (int round = 0; round < 64; ++round) {
        uint64_t r0 = splitmix64(st), r1 = splitmix64(st);
        uint64_t r2 = splitmix64(st), r3 = splitmix64(st);
        int f0 = (int)(((uint64_t)(uint32_t)r0 * (uint32_t)NF) >> 32);
        int f1 = (int)(((uint64_t)(uint32_t)r1 * (uint32_t)NF) >> 32);
        int f2 = (int)(((uint64_t)(uint32_t)r2 * (uint32_t)NF) >> 32);
        int f3 = (int)(((uint64_t)(uint32_t)r3 * (uint32_t)NF) >> 32);
        float a0 = am[f0], a1 = am[f1], a2 = am[f2], a3 = am[f3];
        float u0 = ((uint32_t)(r0 >> 40)) * (1.f/16777216.f);
        float u1 = ((uint32_t)(r1 >> 40)) * (1.f/16777216.f);
        float u2 = ((uint32_t)(r2 >> 40)) * (1.f/16777216.f);
        float u3 = ((uint32_t)(r3 >> 40)) * (1.f/16777216.f);
        if (u0 * maxA <= a0) { f = f0; break; }
        if (u1 * maxA <= a1) { f = f1; break; }
        if (u2 * maxA <= a2) { f = f2; break; }
        if (u3 * maxA <= a3) { f = f3; break; }
        f = f3;   // fallback (practically unreachable)
    }
    // analytic face -> vertex indices (matches _grid_faces order)
    int i0, i1, i2;
    if (f < FH) {
        int c = f;  int i = c / 255, j = c - i*255;  int v = i*GSZ + j;
        i0 = v; i1 = v + 1; i2 = v + GSZ;                    // (v00, v01, v10)
    } else {
        int c = f - FH;  int i = c / 255, j = c - i*255;  int v = i*GSZ + j;
        i0 = v + 1; i1 = v + GSZ + 1; i2 = v + GSZ;          // (v01, v11, v10)
    }
    F3 v0 = ldv3(verts, i0), v1 = ldv3(verts, i1), v2 = ldv3(verts, i2);
    uint64_t r = splitmix64(st);
    float u0 = ((uint32_t)r >> 8) * (1.f/16777216.f);
    float u1 = ((uint32_t)(r >> 32) >> 8) * (1.f/16777216.f);
    float su = sqrtf(u0);
    float w0 = 1.f - su, w1 = su * (1.f - u1), w2 = su * u1;
    float X = w0*v0.x + w1*v1.x + w2*v2.x;
    float Y = w0*v0.y + w1*v1.y + w2*v2.y;
    float Z = w0*v0.z + w1*v1.z + w2*v2.z;
    samples[gid] = make_float4(X, Y, Z, X*X + Y*Y + Z*Z);
}

// ---------------------------------------------------------------------------
// final fp64 accumulation; run by the ONE block that drains the global ticket.
__device__ __forceinline__ void final_accum(const float* chamPart, int nCh,
                                            const float* partE, int nE,
                                            const float* partP, int nP,
                                            const float* partV, int nL,
                                            int B, int E, int P, float* out) {
    const volatile float* cp = chamPart;
    const volatile float* pe = partE;
    const volatile float* pp = partP;
    const volatile float* pv = partV;
    double aC = 0, aE = 0, aP = 0, aL = 0;
    for (int k = threadIdx.x; k < nCh; k += 256) aC += (double)cp[k];
    for (int k = threadIdx.x; k < nE;  k += 256) aE += (double)pe[k];
    for (int k = threadIdx.x; k < nP;  k += 256) aP += (double)pp[k];
    for (int k = threadIdx.x; k < nL;  k += 256) aL += (double)pv[k];
    __shared__ double sd[4][4];
    double v[4] = {aC, aE, aP, aL};
    int lane = threadIdx.x & 63, w = threadIdx.x >> 6;
    #pragma unroll
    for (int r = 0; r < 4; ++r) {
        double x = v[r];
        #pragma unroll
        for (int o = 32; o > 0; o >>= 1) x += __shfl_down(x, o, 64);
        if (lane == 0) sd[r][w] = x;
    }
    __syncthreads();
    if (threadIdx.x == 0) {
        double bn = (double)B * NS;
        double ch = (sd[0][0]+sd[0][1]+sd[0][2]+sd[0][3]) / bn;  // both dirs / (B*NS)
        double ed = (sd[1][0]+sd[1][1]+sd[1][2]+sd[1][3]) / ((double)B * E);
        double no = (sd[2][0]+sd[2][1]+sd[2][2]+sd[2][3]) / ((double)B * P);
        double la = (sd[3][0]+sd[3][1]+sd[3][2]+sd[3][3]) / ((double)B * NV);
        double loss = ch + ed + 0.1*no + 0.1*la;
        out[0] = (float)loss; out[1] = (float)ch; out[2] = (float)ed;
        out[3] = (float)no;   out[4] = (float)la;
    }
}

// ---------------------------------------------------------------------------
// k_heavy: everything after sampling in ONE kernel.
//   bx <  32 : chamfer partial mins. dir = bx>>4, q = bx&15. Each thread owns
//              8 src points (halves LDS tile traffic vs 4). The LAST of the 16
//              q-blocks per (dir,b) group (ticket) combines the 16 partial-min
//              slices and writes chamPart[g] — overlapped with other blocks.
//   bx >= 32 : edge/normal/laplacian losses, analytic grid topology.
// The global-last block (ticket over all blocks) does the fp64 finish.
// ctrl[0] = global ticket; ctrl[1+g] = group tickets (g = dir*B+b < 16).
__global__ void k_heavy(const float* __restrict__ vp,
                        const float4* __restrict__ samples,
                        int B, int E, int P, int nbE, int nbP,
                        float* __restrict__ minpart,
                        float* __restrict__ partE, float* __restrict__ partP,
                        float* __restrict__ partV,
                        float* __restrict__ chamPart,
                        unsigned* __restrict__ ctrl,
                        float* __restrict__ out) {
    int bx = blockIdx.x, b = blockIdx.y;
    int totalBlocks = gridDim.x * gridDim.y;

    if (bx < 32) {
        // ---- chamfer partial mins ----
        int dir = bx >> 4, q = bx & 15;
        int g = dir*B + b;
        const float4* src = samples + ((size_t)dir*B + b)*NS;
        const float4* dst = samples + ((size_t)(1-dir)*B + b)*NS;

        __shared__ float4 tile[128];
        if (threadIdx.x < 128) tile[threadIdx.x] = dst[q*128 + threadIdx.x];

        float nx[8], ny[8], nz[8], xx[8], mn[8];
        #pragma unroll
        for (int k = 0; k < 8; ++k) {
            float4 sp = src[k*256 + threadIdx.x];
            nx[k] = -2.f*sp.x; ny[k] = -2.f*sp.y; nz[k] = -2.f*sp.z;
            xx[k] = sp.w;
            mn[k] = 3.402823466e38f;
        }
        __syncthreads();
        #pragma unroll 2
        for (int j = 0; j < 128; ++j) {
            float4 t = tile[j];
            #pragma unroll
            for (int k = 0; k < 8; ++k) {
                float d = fmaf(nx[k], t.x, t.w);
                d = fmaf(ny[k], t.y, d);
                d = fmaf(nz[k], t.z, d);
                mn[k] = fminf(mn[k], d);
            }
        }
        float* outp = minpart + ((size_t)g*16 + q)*NS;
        #pragma unroll
        for (int k = 0; k < 8; ++k)
            outp[k*256 + threadIdx.x] = mn[k] + xx[k];

        // release our minpart slice, take group ticket
        __threadfence();
        __syncthreads();
        __shared__ unsigned tk;
        if (threadIdx.x == 0) tk = atomicAdd(&ctrl[1+g], 1u);
        __syncthreads();
        if (tk == 15u) {
            __threadfence();          // acquire: see the other 15 blocks' mins
            float acc = 0.f;
            const float* mp = minpart + (size_t)g*16*NS;
            #pragma unroll
            for (int kk = 0; kk < 8; ++kk) {
                int i = kk*256 + threadIdx.x;
                float m = 3.402823466e38f;
                #pragma unroll
                for (int q2 = 0; q2 < 16; ++q2)
                    m = fminf(m, mp[(size_t)q2*NS + i]);
                acc += m;
            }
            float s = blockReduceSum256(acc);
            if (threadIdx.x == 0) chamPart[g] = s;
        }
    } else {
        // ---- mesh losses ----
        int mx = bx - 32;
        const float* verts = vp + (size_t)b*NV*3;
        float acc = 0.f;
        if (mx < nbE) {
            // edge loss, analytic 3-class enumeration
            int base = mx*(256*CH);
            for (int c = 0; c < CH; ++c) {
                int e = base + c*256 + threadIdx.x;
                if (e < E) {
                    int i0, i1;
                    if (e < EH) {                       // horizontal (r,c)-(r,c+1)
                        int r = e / 255, cc = e - r*255;
                        i0 = r*GSZ + cc; i1 = i0 + 1;
                    } else if (e < EH + EV) {           // vertical (i,j)-(i+1,j)
                        int e2 = e - EH;
                        int i = e2 >> 8, j = e2 & 255;  // 255x256
                        i0 = i*GSZ + j; i1 = i0 + GSZ;
                    } else {                            // diagonal (i,j+1)-(i+1,j)
                        int e2 = e - (EH + EV);
                        int i = e2 / 255, j = e2 - i*255;
                        i0 = i*GSZ + j + 1; i1 = (i+1)*GSZ + j;
                    }
                    F3 d = f3sub(ldv3(verts, i0), ldv3(verts, i1));
                    acc += f3dot(d, d);
                }
            }
            float s = blockReduceSum256(acc);
            if (threadIdx.x == 0) partE[(size_t)mx*B + b] = s;
        } else if (mx < nbE + nbP) {
            // normal consistency, analytic 3-class enumeration of interior edges
            int base = (mx - nbE)*(256*CH);
            for (int c = 0; c < CH; ++c) {
                int p = base + c*256 + threadIdx.x;
                if (p < P) {
                    int iv0, iv1, ia, ib;
                    if (p < PH) {                       // horiz edge, r in [1,254]
                        int r = p / 255 + 1, cc = p - (r-1)*255;
                        iv0 = r*GSZ + cc; iv1 = iv0 + 1;
                        ia = iv0 + GSZ;                 // (r+1,c)
                        ib = iv0 - GSZ + 1;             // (r-1,c+1)
                    } else if (p < PH + PV) {           // vert edge, j in [1,254]
                        int p2 = p - PH;
                        int r = p2 / 254, j = p2 - r*254 + 1;
                        iv0 = r*GSZ + j; iv1 = iv0 + GSZ;
                        ia = iv0 + 1;                   // (r,j+1)
                        ib = iv0 + GSZ - 1;             // (r+1,j-1)
                    } else {                            // diagonal edge of cell (i,j)
                        int p2 = p - (PH + PV);
                        int i = p2 / 255, j = p2 - i*255;
                        iv0 = i*GSZ + j + 1;            // (i,j+1)
                        iv1 = (i+1)*GSZ + j;            // (i+1,j)
                        ia = i*GSZ + j;                 // (i,j)
                        ib = (i+1)*GSZ + j + 1;         // (i+1,j+1)
                    }
                    F3 v0 = ldv3(verts, iv0), v1 = ldv3(verts, iv1);
                    F3 a = ldv3(verts, ia), bb = ldv3(verts, ib);
                    F3 e = f3sub(v1, v0);
                    F3 n0 = f3cross(e, f3sub(a, v0));
                    F3 n1 = f3cross(f3sub(bb, v0), e);     // == -cross(e, bb-v0)
                    float num = f3dot(n0, n1);
                    float den2 = fmaxf(f3dot(n0, n0), 1e-16f) * fmaxf(f3dot(n1, n1), 1e-16f);
                    acc += 1.f - num * rsqrtf(den2);
                }
            }
            float s = blockReduceSum256(acc);
            if (threadIdx.x == 0) partP[(size_t)(mx - nbE)*B + b] = s;
        } else {
            int base = (mx - nbE - nbP)*(256*CH);
            for (int c = 0; c < CH; ++c) {
                int idx = base + c*256 + threadIdx.x;      // < NV always (nbV exact)
                int i = idx >> 8, j = idx & 255;
                F3 ctr = ldv3(verts, idx);
                float nx = 0.f, ny = 0.f, nz = 0.f; int deg = 0;
                #define ADDN(ii, jj) { F3 n_ = ldv3(verts, (ii)*GSZ + (jj)); \
                                       nx += n_.x; ny += n_.y; nz += n_.z; ++deg; }
                if (j > 0)               ADDN(i, j-1);
                if (j < GSZ-1)           ADDN(i, j+1);
                if (i > 0)               ADDN(i-1, j);
                if (i < GSZ-1)           ADDN(i+1, j);
                if (i < GSZ-1 && j > 0)  ADDN(i+1, j-1);   // anti-diagonal
                if (i > 0 && j < GSZ-1)  ADDN(i-1, j+1);
                #undef ADDN
                float inv = 1.f / (float)deg;
                float lx = nx*inv - ctr.x, ly = ny*inv - ctr.y, lz = nz*inv - ctr.z;
                acc += sqrtf(lx*lx + ly*ly + lz*lz);
            }
            float s = blockReduceSum256(acc);
            if (threadIdx.x == 0) partV[(size_t)(mx - nbE - nbP)*B + b] = s;
        }
    }

    // ---- global ticket; last block does the fp64 finish ----
    __threadfence();
    __syncthreads();
    __shared__ unsigned gt;
    if (threadIdx.x == 0) gt = atomicAdd(&ctrl[0], 1u);
    __syncthreads();
    if (gt != (unsigned)(totalBlocks - 1)) return;
    __threadfence();   // acquire all partials
    final_accum(chamPart, 2*B, partE, nbE*B, partP, nbP*B, partV,
                (NV/(256*CH))*B, B, E, P, out);
}

extern "C" void kernel_launch(void* const* d_in, const int* in_sizes, int n_in,
                              void* d_out, int out_size, void* d_ws, size_t ws_size,
                              hipStream_t stream) {
    const float* vp = (const float*)d_in[0];
    const float* vt = (const float*)d_in[1];
    const int B = in_sizes[0] / (3*NV);
    const int E = in_sizes[3] / 2;   // 195585 (denominator; topology is analytic)
    const int P = in_sizes[4] / 4;   // 194565

    char* ws = (char*)d_ws;
    size_t off = 0;
    auto alloc = [&](size_t bytes) -> void* {
        void* p = ws + off;
        off = (off + bytes + 255) & ~(size_t)255;
        return p;
    };
    float*    areas    = (float*)   alloc((size_t)2*B*NF*sizeof(float));      // 8.3 MB
    float4*   samples  = (float4*)  alloc((size_t)2*B*NS*sizeof(float4));     // 1.0 MB
    float*    minpart  = (float*)   alloc((size_t)2*B*16*NS*sizeof(float));   // 2.1 MB
    float*    blockmax = (float*)   alloc(8192*sizeof(float));
    float*    chamPart = (float*)   alloc(256*sizeof(float));
    float*    partE    = (float*)   alloc(2048*sizeof(float));
    float*    partP    = (float*)   alloc(2048*sizeof(float));
    float*    partV    = (float*)   alloc(1024*sizeof(float));
    unsigned* ctrl     = (unsigned*)alloc(256);   // [0]=global, [1..16]=groups

    int nbm = (2*B*CELLS + 255)/256;                    // k_area blocks (4065)
    k_area<<<nbm, 256, 0, stream>>>(vp, vt, B, areas, blockmax, ctrl);
    k_sample<<<(2*B*NS)/256, 256, 0, stream>>>(vp, vt, B, areas, blockmax, nbm, samples);
    int nbE = (E + 256*CH - 1)/(256*CH);
    int nbP = (P + 256*CH - 1)/(256*CH);
    int nbV = NV/(256*CH);
    dim3 gh(32 + nbE + nbP + nbV, B);
    k_heavy<<<gh, 256, 0, stream>>>(vp, samples, B, E, P, nbE, nbP,
                                    minpart, partE, partP, partV,
                                    chamPart, ctrl, (float*)d_out);
}

// Round 8
// 152.548 us; speedup vs baseline: 1.9376x; 1.9376x over previous
//
#include <hip/hip_runtime.h>
#include <stdint.h>

#define GSZ 256
#define NV (GSZ*GSZ)
#define NS 2048
#define CELLS (255*255)          // 65025 cells per mesh
#define FH CELLS                 // first-half face count
#define NF (2*CELLS)             // 130050 faces per mesh
#define CH 8                     // chunks per mesh-loss block

// analytic grid-topology counts (verified against reference dedup):
// edges:  horiz 256*255=65280 | vert 255*256=65280 | diag 255*255=65025  -> 195585
// pairs:  horiz 254*255=64770 | vert 255*254=64770 | diag 255*255=65025  -> 194565
#define EH 65280
#define EV 65280
#define PH 64770
#define PV 64770

struct F3 { float x, y, z; };

__device__ __forceinline__ F3 ldv3(const float* __restrict__ p, int idx) {
    const float* q = p + 3*(size_t)idx;
    F3 r; r.x = q[0]; r.y = q[1]; r.z = q[2]; return r;
}
__device__ __forceinline__ F3 f3sub(F3 a, F3 b) { return F3{a.x-b.x, a.y-b.y, a.z-b.z}; }
__device__ __forceinline__ F3 f3cross(F3 a, F3 b) {
    return F3{a.y*b.z - a.z*b.y, a.z*b.x - a.x*b.z, a.x*b.y - a.y*b.x};
}
__device__ __forceinline__ float f3dot(F3 a, F3 b) { return a.x*b.x + a.y*b.y + a.z*b.z; }

__device__ __forceinline__ uint64_t splitmix64(uint64_t& s) {
    s += 0x9E3779B97F4A7C15ULL;
    uint64_t z = s;
    z = (z ^ (z >> 30)) * 0xBF58476D1CE4E5B9ULL;
    z = (z ^ (z >> 27)) * 0x94D049BB133111EBULL;
    return z ^ (z >> 31);
}

// result valid on thread 0 only; blockDim.x == 256
__device__ __forceinline__ float blockReduceSum256(float v) {
    __shared__ float s[4];
    int lane = threadIdx.x & 63, w = threadIdx.x >> 6;
    #pragma unroll
    for (int o = 32; o > 0; o >>= 1) v += __shfl_down(v, o, 64);
    if (lane == 0) s[w] = v;
    __syncthreads();
    if (threadIdx.x == 0) v = s[0] + s[1] + s[2] + s[3];
    return v;
}

// ---------------------------------------------------------------------------
// k_area: per-cell face areas for both clouds + per-block max written to a
// PRIVATE slot (plain store, NOT a same-address atomic: 4065 single-address
// atomicMax RMWs serialized = +42us — round-4 lesson; likewise grid-wide
// __threadfence + global ticket at 2048 blocks = +150us — round-7 lesson).
// Also zeroes the last-block ticket counter used by k_redfin.
__global__ void k_area(const float* __restrict__ vp, const float* __restrict__ vt,
                       int B, float* __restrict__ areas, float* __restrict__ blockmax,
                       unsigned* __restrict__ counter) {
    if (blockIdx.x == 0 && threadIdx.x == 0) *counter = 0u;
    int gid = blockIdx.x*256 + threadIdx.x;
    int total = 2*B*CELLS;
    float mloc = 0.f;
    if (gid < total) {
        int m = gid / CELLS;              // mesh id (0..2B)
        int c = gid - m*CELLS;            // cell id
        int i = c / 255, j = c - i*255;
        const float* verts = (m < B ? vp + (size_t)m*NV*3
                                    : vt + (size_t)(m-B)*NV*3);
        int b00 = i*GSZ + j;
        F3 v00 = ldv3(verts, b00);
        F3 v01 = ldv3(verts, b00+1);
        F3 v10 = ldv3(verts, b00+GSZ);
        F3 v11 = ldv3(verts, b00+GSZ+1);
        F3 c1 = f3cross(f3sub(v01, v00), f3sub(v10, v00));
        F3 c2 = f3cross(f3sub(v11, v01), f3sub(v10, v01));
        float a1 = 0.5f * sqrtf(f3dot(c1, c1));
        float a2 = 0.5f * sqrtf(f3dot(c2, c2));
        size_t base = (size_t)m*NF;
        areas[base + c]      = a1;   // face f1[c]
        areas[base + FH + c] = a2;   // face f2[c]
        mloc = fmaxf(a1, a2);
    }
    #pragma unroll
    for (int o = 32; o > 0; o >>= 1) mloc = fmaxf(mloc, __shfl_down(mloc, o, 64));
    __shared__ float s[4];
    int lane = threadIdx.x & 63, w = threadIdx.x >> 6;
    if (lane == 0) s[w] = mloc;
    __syncthreads();
    if (threadIdx.x == 0)
        blockmax[blockIdx.x] = fmaxf(fmaxf(s[0], s[1]), fmaxf(s[2], s[3]));
}

// ---------------------------------------------------------------------------
// k_sample: area-weighted rejection sampling, materialized ONCE (regen-in-
// consumer was an 18x redundant gather storm — round-3 lesson). Output is
// float4 with w=|p|^2 for the FMA-form chamfer distance.
// grid: (2*B*NS)/256 = 128 blocks
__global__ void k_sample(const float* __restrict__ vp, const float* __restrict__ vt,
                         int B, const float* __restrict__ areas,
                         const float* __restrict__ blockmax, int nbm,
                         float4* __restrict__ samples) {
    // block-wide reduce of global max area (L2-hot, ~16 coalesced loads/thread)
    float m = 0.f;
    for (int k = threadIdx.x; k < nbm; k += 256) m = fmaxf(m, blockmax[k]);
    #pragma unroll
    for (int o = 32; o > 0; o >>= 1) m = fmaxf(m, __shfl_down(m, o, 64));
    __shared__ float s[4];
    int lane = threadIdx.x & 63, w = threadIdx.x >> 6;
    if (lane == 0) s[w] = m;
    __syncthreads();
    __shared__ float sMaxA;
    if (threadIdx.x == 0) sMaxA = fmaxf(fmaxf(s[0], s[1]), fmaxf(s[2], s[3]));
    __syncthreads();
    float maxA = sMaxA;

    int gid = blockIdx.x*256 + threadIdx.x;       // 0 .. 2*B*NS
    int cloud = gid / (B*NS);
    int rem = gid - cloud*(B*NS);
    int b = rem / NS;
    const float* verts = (cloud ? vt : vp) + (size_t)b*NV*3;
    const float* am = areas + (size_t)(cloud*B + b)*NF;

    uint64_t st = ((uint64_t)(gid + 1) * 0x9E3779B97F4A7C15ULL) ^ 0xC0FFEE123456789ULL;
    int f = 0;
    for (int round = 0; round < 64; ++round) {
        uint64_t r0 = splitmix64(st), r1 = splitmix64(st);
        uint64_t r2 = splitmix64(st), r3 = splitmix64(st);
        int f0 = (int)(((uint64_t)(uint32_t)r0 * (uint32_t)NF) >> 32);
        int f1 = (int)(((uint64_t)(uint32_t)r1 * (uint32_t)NF) >> 32);
        int f2 = (int)(((uint64_t)(uint32_t)r2 * (uint32_t)NF) >> 32);
        int f3 = (int)(((uint64_t)(uint32_t)r3 * (uint32_t)NF) >> 32);
        float a0 = am[f0], a1 = am[f1], a2 = am[f2], a3 = am[f3];
        float u0 = ((uint32_t)(r0 >> 40)) * (1.f/16777216.f);
        float u1 = ((uint32_t)(r1 >> 40)) * (1.f/16777216.f);
        float u2 = ((uint32_t)(r2 >> 40)) * (1.f/16777216.f);
        float u3 = ((uint32_t)(r3 >> 40)) * (1.f/16777216.f);
        if (u0 * maxA <= a0) { f = f0; break; }
        if (u1 * maxA <= a1) { f = f1; break; }
        if (u2 * maxA <= a2) { f = f2; break; }
        if (u3 * maxA <= a3) { f = f3; break; }
        f = f3;   // fallback (practically unreachable)
    }
    // analytic face -> vertex indices (matches _grid_faces order)
    int i0, i1, i2;
    if (f < FH) {
        int c = f;  int i = c / 255, j = c - i*255;  int v = i*GSZ + j;
        i0 = v; i1 = v + 1; i2 = v + GSZ;                    // (v00, v01, v10)
    } else {
        int c = f - FH;  int i = c / 255, j = c - i*255;  int v = i*GSZ + j;
        i0 = v + 1; i1 = v + GSZ + 1; i2 = v + GSZ;          // (v01, v11, v10)
    }
    F3 v0 = ldv3(verts, i0), v1 = ldv3(verts, i1), v2 = ldv3(verts, i2);
    uint64_t r = splitmix64(st);
    float u0 = ((uint32_t)r >> 8) * (1.f/16777216.f);
    float u1 = ((uint32_t)(r >> 32) >> 8) * (1.f/16777216.f);
    float su = sqrtf(u0);
    float w0 = 1.f - su, w1 = su * (1.f - u1), w2 = su * u1;
    float X = w0*v0.x + w1*v1.x + w2*v2.x;
    float Y = w0*v0.y + w1*v1.y + w2*v2.y;
    float Z = w0*v0.z + w1*v1.z + w2*v2.z;
    samples[gid] = make_float4(X, Y, Z, X*X + Y*Y + Z*Z);
}

// ---------------------------------------------------------------------------
// k_heavy: fused chamfer partial-min (bx < 32 per b) + edge/normal/laplacian
// losses (bx >= 32). Chamfer: 8 src points/thread (each LDS tile read feeds
// 8 pairs — halves LDS traffic vs 4/thread). FMA form:
//   |x-y|^2 = |x|^2 + (|y|^2 - 2 x.y)   -> 3 FMA + 1 min per pair.
// NO grid-wide fences/tickets here (round-7 lesson).
__global__ void k_heavy(const float* __restrict__ vp,
                        const float4* __restrict__ samples,
                        int B, int E, int P, int nbE, int nbP,
                        float* __restrict__ minpart,
                        float* __restrict__ partE, float* __restrict__ partP,
                        float* __restrict__ partV) {
    int bx = blockIdx.x, b = blockIdx.y;
    if (bx < 32) {
        // ---- chamfer partial mins: dir = bx>>4, q = dst chunk ----
        int dir = bx >> 4, q = bx & 15;
        const float4* src = samples + ((size_t)dir*B + b)*NS;
        const float4* dst = samples + ((size_t)(1-dir)*B + b)*NS;

        __shared__ float4 tile[128];
        if (threadIdx.x < 128) tile[threadIdx.x] = dst[q*128 + threadIdx.x];

        float nx[8], ny[8], nz[8], xx[8], mn[8];
        #pragma unroll
        for (int k = 0; k < 8; ++k) {
            float4 sp = src[k*256 + threadIdx.x];
            nx[k] = -2.f*sp.x; ny[k] = -2.f*sp.y; nz[k] = -2.f*sp.z;
            xx[k] = sp.w;
            mn[k] = 3.402823466e38f;
        }
        __syncthreads();
        #pragma unroll 2
        for (int j = 0; j < 128; ++j) {
            float4 t = tile[j];
            #pragma unroll
            for (int k = 0; k < 8; ++k) {
                float d = fmaf(nx[k], t.x, t.w);
                d = fmaf(ny[k], t.y, d);
                d = fmaf(nz[k], t.z, d);
                mn[k] = fminf(mn[k], d);
            }
        }
        float* outp = minpart + (((size_t)(dir*B + b)*16) + q)*NS;
        #pragma unroll
        for (int k = 0; k < 8; ++k)
            outp[k*256 + threadIdx.x] = mn[k] + xx[k];
        return;
    }

    // ---- mesh losses ----
    int mx = bx - 32;
    const float* verts = vp + (size_t)b*NV*3;
    float acc = 0.f;
    if (mx < nbE) {
        // edge loss, analytic 3-class enumeration
        int base = mx*(256*CH);
        for (int c = 0; c < CH; ++c) {
            int e = base + c*256 + threadIdx.x;
            if (e < E) {
                int i0, i1;
                if (e < EH) {                       // horizontal (r,c)-(r,c+1)
                    int r = e / 255, cc = e - r*255;
                    i0 = r*GSZ + cc; i1 = i0 + 1;
                } else if (e < EH + EV) {           // vertical (i,j)-(i+1,j)
                    int e2 = e - EH;
                    int i = e2 >> 8, j = e2 & 255;  // 255x256
                    i0 = i*GSZ + j; i1 = i0 + GSZ;
                } else {                            // diagonal (i,j+1)-(i+1,j)
                    int e2 = e - (EH + EV);
                    int i = e2 / 255, j = e2 - i*255;
                    i0 = i*GSZ + j + 1; i1 = (i+1)*GSZ + j;
                }
                F3 d = f3sub(ldv3(verts, i0), ldv3(verts, i1));
                acc += f3dot(d, d);
            }
        }
        float s = blockReduceSum256(acc);
        if (threadIdx.x == 0) partE[(size_t)mx*B + b] = s;
    } else if (mx < nbE + nbP) {
        // normal consistency, analytic 3-class enumeration of interior edges
        int base = (mx - nbE)*(256*CH);
        for (int c = 0; c < CH; ++c) {
            int p = base + c*256 + threadIdx.x;
            if (p < P) {
                int iv0, iv1, ia, ib;
                if (p < PH) {                       // horiz edge, r in [1,254]
                    int r = p / 255 + 1, cc = p - (r-1)*255;
                    iv0 = r*GSZ + cc; iv1 = iv0 + 1;
                    ia = iv0 + GSZ;                 // (r+1,c)
                    ib = iv0 - GSZ + 1;             // (r-1,c+1)
                } else if (p < PH + PV) {           // vert edge, j in [1,254]
                    int p2 = p - PH;
                    int r = p2 / 254, j = p2 - r*254 + 1;
                    iv0 = r*GSZ + j; iv1 = iv0 + GSZ;
                    ia = iv0 + 1;                   // (r,j+1)
                    ib = iv0 + GSZ - 1;             // (r+1,j-1)
                } else {                            // diagonal edge of cell (i,j)
                    int p2 = p - (PH + PV);
                    int i = p2 / 255, j = p2 - i*255;
                    iv0 = i*GSZ + j + 1;            // (i,j+1)
                    iv1 = (i+1)*GSZ + j;            // (i+1,j)
                    ia = i*GSZ + j;                 // (i,j)
                    ib = (i+1)*GSZ + j + 1;         // (i+1,j+1)
                }
                F3 v0 = ldv3(verts, iv0), v1 = ldv3(verts, iv1);
                F3 a = ldv3(verts, ia), bb = ldv3(verts, ib);
                F3 e = f3sub(v1, v0);
                F3 n0 = f3cross(e, f3sub(a, v0));
                F3 n1 = f3cross(f3sub(bb, v0), e);     // == -cross(e, bb-v0)
                float num = f3dot(n0, n1);
                float den2 = fmaxf(f3dot(n0, n0), 1e-16f) * fmaxf(f3dot(n1, n1), 1e-16f);
                acc += 1.f - num * rsqrtf(den2);
            }
        }
        float s = blockReduceSum256(acc);
        if (threadIdx.x == 0) partP[(size_t)(mx - nbE)*B + b] = s;
    } else {
        int base = (mx - nbE - nbP)*(256*CH);
        for (int c = 0; c < CH; ++c) {
            int idx = base + c*256 + threadIdx.x;      // < NV always (nbV exact)
            int i = idx >> 8, j = idx & 255;
            F3 ctr = ldv3(verts, idx);
            float nx = 0.f, ny = 0.f, nz = 0.f; int deg = 0;
            #define ADDN(ii, jj) { F3 n_ = ldv3(verts, (ii)*GSZ + (jj)); \
                                   nx += n_.x; ny += n_.y; nz += n_.z; ++deg; }
            if (j > 0)               ADDN(i, j-1);
            if (j < GSZ-1)           ADDN(i, j+1);
            if (i > 0)               ADDN(i-1, j);
            if (i < GSZ-1)           ADDN(i+1, j);
            if (i < GSZ-1 && j > 0)  ADDN(i+1, j-1);   // anti-diagonal
            if (i > 0 && j < GSZ-1)  ADDN(i-1, j+1);
            #undef ADDN
            float inv = 1.f / (float)deg;
            float lx = nx*inv - ctr.x, ly = ny*inv - ctr.y, lz = nz*inv - ctr.z;
            acc += sqrtf(lx*lx + ly*ly + lz*lz);
        }
        float s = blockReduceSum256(acc);
        if (threadIdx.x == 0) partV[(size_t)(mx - nbE - nbP)*B + b] = s;
    }
}

// ---------------------------------------------------------------------------
// k_redfin: combine 16 dst-chunk partial mins per src point, block partial
// sums; the LAST block (atomic counter: only 128 same-address adds + 128
// fences — cheap at this scale) does the fp64 finish and writes 5 outputs.
// grid: (2*B*NS)/256 = 128 blocks
__global__ void k_redfin(const float* __restrict__ minpart, int B,
                         const float* __restrict__ partE, int nE,
                         const float* __restrict__ partP, int nP,
                         const float* __restrict__ partV, int nL,
                         int E, int P,
                         float* __restrict__ chamPart,
                         unsigned* __restrict__ counter,
                         float* __restrict__ out) {
    int gid = blockIdx.x*256 + threadIdx.x;
    int dir = gid / (B*NS);
    int rem = gid - dir*(B*NS);
    int b = rem / NS, i = rem - b*NS;
    const float* p = minpart + (size_t)(dir*B + b)*16*NS + i;
    float mn = 3.402823466e38f;
    #pragma unroll
    for (int q = 0; q < 16; ++q) mn = fminf(mn, p[(size_t)q*NS]);
    float sm = blockReduceSum256(mn);
    if (threadIdx.x == 0) chamPart[blockIdx.x] = sm;   // blocks 0..63 dir0, 64..127 dir1

    // last-block-done detection
    __shared__ unsigned sTicket;
    if (threadIdx.x == 0) {
        __threadfence();
        sTicket = atomicAdd(counter, 1u);
    }
    __syncthreads();
    if (sTicket != (unsigned)(gridDim.x - 1)) return;
    __threadfence();

    // ---- final fp64 accumulation (single surviving block) ----
    const volatile float* cp = chamPart;               // peer-block results
    double a0 = 0, a1 = 0, aE = 0, aP = 0, aL = 0;
    for (int k = threadIdx.x; k < 64;  k += 256) a0 += (double)cp[k];
    for (int k = 64 + threadIdx.x; k < 128; k += 256) a1 += (double)cp[k];
    for (int k = threadIdx.x; k < nE; k += 256) aE += (double)partE[k];
    for (int k = threadIdx.x; k < nP; k += 256) aP += (double)partP[k];
    for (int k = threadIdx.x; k < nL; k += 256) aL += (double)partV[k];
    __shared__ double sd[5][4];
    double v[5] = {a0, a1, aE, aP, aL};
    int lane = threadIdx.x & 63, w = threadIdx.x >> 6;
    #pragma unroll
    for (int r = 0; r < 5; ++r) {
        double x = v[r];
        #pragma unroll
        for (int o = 32; o > 0; o >>= 1) x += __shfl_down(x, o, 64);
        if (lane == 0) sd[r][w] = x;
    }
    __syncthreads();
    if (threadIdx.x == 0) {
        double bn = (double)B * NS;
        double ch = (sd[0][0]+sd[0][1]+sd[0][2]+sd[0][3]) / bn
                  + (sd[1][0]+sd[1][1]+sd[1][2]+sd[1][3]) / bn;
        double ed = (sd[2][0]+sd[2][1]+sd[2][2]+sd[2][3]) / ((double)B * E);
        double no = (sd[3][0]+sd[3][1]+sd[3][2]+sd[3][3]) / ((double)B * P);
        double la = (sd[4][0]+sd[4][1]+sd[4][2]+sd[4][3]) / ((double)B * NV);
        double loss = ch + ed + 0.1*no + 0.1*la;
        out[0] = (float)loss; out[1] = (float)ch; out[2] = (float)ed;
        out[3] = (float)no;   out[4] = (float)la;
    }
}

extern "C" void kernel_launch(void* const* d_in, const int* in_sizes, int n_in,
                              void* d_out, int out_size, void* d_ws, size_t ws_size,
                              hipStream_t stream) {
    const float* vp = (const float*)d_in[0];
    const float* vt = (const float*)d_in[1];
    const int B = in_sizes[0] / (3*NV);
    const int E = in_sizes[3] / 2;   // 195585 (denominator; topology is analytic)
    const int P = in_sizes[4] / 4;   // 194565

    char* ws = (char*)d_ws;
    size_t off = 0;
    auto alloc = [&](size_t bytes) -> void* {
        void* p = ws + off;
        off = (off + bytes + 255) & ~(size_t)255;
        return p;
    };
    float*    areas    = (float*)   alloc((size_t)2*B*NF*sizeof(float));      // 8.3 MB
    float4*   samples  = (float4*)  alloc((size_t)2*B*NS*sizeof(float4));     // 1.0 MB
    float*    minpart  = (float*)   alloc((size_t)2*B*16*NS*sizeof(float));   // 2.1 MB
    float*    blockmax = (float*)   alloc(8192*sizeof(float));
    float*    chamPart = (float*)   alloc(256*sizeof(float));
    float*    partE    = (float*)   alloc(2048*sizeof(float));
    float*    partP    = (float*)   alloc(2048*sizeof(float));
    float*    partV    = (float*)   alloc(1024*sizeof(float));
    unsigned* counter  = (unsigned*)alloc(256);

    int nbm = (2*B*CELLS + 255)/256;                    // k_area blocks (4065)
    k_area<<<nbm, 256, 0, stream>>>(vp, vt, B, areas, blockmax, counter);
    k_sample<<<(2*B*NS)/256, 256, 0, stream>>>(vp, vt, B, areas, blockmax, nbm, samples);
    int nbE = (E + 256*CH - 1)/(256*CH);
    int nbP = (P + 256*CH - 1)/(256*CH);
    int nbV = NV/(256*CH);
    dim3 gh(32 + nbE + nbP + nbV, B);
    k_heavy<<<gh, 256, 0, stream>>>(vp, samples, B, E, P, nbE, nbP,
                                    minpart, partE, partP, partV);
    k_redfin<<<(2*B*NS)/256, 256, 0, stream>>>(minpart, B, partE, nbE*B,
                                               partP, nbP*B, partV, nbV*B,
                                               E, P, chamPart, counter,
                                               (float*)d_out);
}

// Round 9
// 136.242 us; speedup vs baseline: 2.1694x; 1.1197x over previous
//
#include <hip/hip_runtime.h>
#include <stdint.h>

#define GSZ 256
#define NV (GSZ*GSZ)
#define NS 2048
#define CELLS (255*255)          // 65025 cells per mesh
#define FH CELLS                 // first-half face count
#define NF (2*CELLS)             // 130050 faces per mesh
#define CH 8                     // chunks per mesh-loss block

// analytic grid-topology counts (verified against reference dedup):
// edges:  horiz 256*255=65280 | vert 255*256=65280 | diag 255*255=65025  -> 195585
// pairs:  horiz 254*255=64770 | vert 255*254=64770 | diag 255*255=65025  -> 194565
#define EH 65280
#define EV 65280
#define PH 64770
#define PV 64770

struct F3 { float x, y, z; };

__device__ __forceinline__ F3 ldv3(const float* __restrict__ p, int idx) {
    const float* q = p + 3*(size_t)idx;
    F3 r; r.x = q[0]; r.y = q[1]; r.z = q[2]; return r;
}
__device__ __forceinline__ F3 f3sub(F3 a, F3 b) { return F3{a.x-b.x, a.y-b.y, a.z-b.z}; }
__device__ __forceinline__ F3 f3cross(F3 a, F3 b) {
    return F3{a.y*b.z - a.z*b.y, a.z*b.x - a.x*b.z, a.x*b.y - a.y*b.x};
}
__device__ __forceinline__ float f3dot(F3 a, F3 b) { return a.x*b.x + a.y*b.y + a.z*b.z; }

__device__ __forceinline__ uint64_t splitmix64(uint64_t& s) {
    s += 0x9E3779B97F4A7C15ULL;
    uint64_t z = s;
    z = (z ^ (z >> 30)) * 0xBF58476D1CE4E5B9ULL;
    z = (z ^ (z >> 27)) * 0x94D049BB133111EBULL;
    return z ^ (z >> 31);
}

// result valid on thread 0 only; blockDim.x == 256
__device__ __forceinline__ float blockReduceSum256(float v) {
    __shared__ float s[4];
    int lane = threadIdx.x & 63, w = threadIdx.x >> 6;
    #pragma unroll
    for (int o = 32; o > 0; o >>= 1) v += __shfl_down(v, o, 64);
    if (lane == 0) s[w] = v;
    __syncthreads();
    if (threadIdx.x == 0) v = s[0] + s[1] + s[2] + s[3];
    return v;
}

// ---------------------------------------------------------------------------
// k_area: per-cell face areas for both clouds + per-block max written to a
// PRIVATE slot (plain store, NOT a same-address atomic: 4065 single-address
// atomicMax RMWs serialized = +42us — round-4 lesson; grid-wide fence+ticket
// at 2048 blocks = +150us — round-7 lesson).
// Also zeroes the last-block ticket counter used by k_redfin.
__global__ void k_area(const float* __restrict__ vp, const float* __restrict__ vt,
                       int B, float* __restrict__ areas, float* __restrict__ blockmax,
                       unsigned* __restrict__ counter) {
    if (blockIdx.x == 0 && threadIdx.x == 0) *counter = 0u;
    int gid = blockIdx.x*256 + threadIdx.x;
    int total = 2*B*CELLS;
    float mloc = 0.f;
    if (gid < total) {
        int m = gid / CELLS;              // mesh id (0..2B)
        int c = gid - m*CELLS;            // cell id
        int i = c / 255, j = c - i*255;
        const float* verts = (m < B ? vp + (size_t)m*NV*3
                                    : vt + (size_t)(m-B)*NV*3);
        int b00 = i*GSZ + j;
        F3 v00 = ldv3(verts, b00);
        F3 v01 = ldv3(verts, b00+1);
        F3 v10 = ldv3(verts, b00+GSZ);
        F3 v11 = ldv3(verts, b00+GSZ+1);
        F3 c1 = f3cross(f3sub(v01, v00), f3sub(v10, v00));
        F3 c2 = f3cross(f3sub(v11, v01), f3sub(v10, v01));
        float a1 = 0.5f * sqrtf(f3dot(c1, c1));
        float a2 = 0.5f * sqrtf(f3dot(c2, c2));
        size_t base = (size_t)m*NF;
        areas[base + c]      = a1;   // face f1[c]
        areas[base + FH + c] = a2;   // face f2[c]
        mloc = fmaxf(a1, a2);
    }
    #pragma unroll
    for (int o = 32; o > 0; o >>= 1) mloc = fmaxf(mloc, __shfl_down(mloc, o, 64));
    __shared__ float s[4];
    int lane = threadIdx.x & 63, w = threadIdx.x >> 6;
    if (lane == 0) s[w] = mloc;
    __syncthreads();
    if (threadIdx.x == 0)
        blockmax[blockIdx.x] = fmaxf(fmaxf(s[0], s[1]), fmaxf(s[2], s[3]));
}

// ---------------------------------------------------------------------------
// k_sample: area-weighted rejection sampling, materialized ONCE (regen-in-
// consumer was an 18x redundant gather storm — round-3 lesson). Output is
// float4 with w=|p|^2 for the FMA-form chamfer distance.
// grid: (2*B*NS)/256 = 128 blocks
__global__ void k_sample(const float* __restrict__ vp, const float* __restrict__ vt,
                         int B, const float* __restrict__ areas,
                         const float* __restrict__ blockmax, int nbm,
                         float4* __restrict__ samples) {
    // block-wide reduce of global max area (L2-hot, ~16 coalesced loads/thread)
    float m = 0.f;
    for (int k = threadIdx.x; k < nbm; k += 256) m = fmaxf(m, blockmax[k]);
    #pragma unroll
    for (int o = 32; o > 0; o >>= 1) m = fmaxf(m, __shfl_down(m, o, 64));
    __shared__ float s[4];
    int lane = threadIdx.x & 63, w = threadIdx.x >> 6;
    if (lane == 0) s[w] = m;
    __syncthreads();
    __shared__ float sMaxA;
    if (threadIdx.x == 0) sMaxA = fmaxf(fmaxf(s[0], s[1]), fmaxf(s[2], s[3]));
    __syncthreads();
    float maxA = sMaxA;

    int gid = blockIdx.x*256 + threadIdx.x;       // 0 .. 2*B*NS
    int cloud = gid / (B*NS);
    int rem = gid - cloud*(B*NS);
    int b = rem / NS;
    const float* verts = (cloud ? vt : vp) + (size_t)b*NV*3;
    const float* am = areas + (size_t)(cloud*B + b)*NF;

    uint64_t st = ((uint64_t)(gid + 1) * 0x9E3779B97F4A7C15ULL) ^ 0xC0FFEE123456789ULL;
    int f = 0;
    for (int round = 0; round < 64; ++round) {
        uint64_t r0 = splitmix64(st), r1 = splitmix64(st);
        uint64_t r2 = splitmix64(st), r3 = splitmix64(st);
        int f0 = (int)(((uint64_t)(uint32_t)r0 * (uint32_t)NF) >> 32);
        int f1 = (int)(((uint64_t)(uint32_t)r1 * (uint32_t)NF) >> 32);
        int f2 = (int)(((uint64_t)(uint32_t)r2 * (uint32_t)NF) >> 32);
        int f3 = (int)(((uint64_t)(uint32_t)r3 * (uint32_t)NF) >> 32);
        float a0 = am[f0], a1 = am[f1], a2 = am[f2], a3 = am[f3];
        float u0 = ((uint32_t)(r0 >> 40)) * (1.f/16777216.f);
        float u1 = ((uint32_t)(r1 >> 40)) * (1.f/16777216.f);
        float u2 = ((uint32_t)(r2 >> 40)) * (1.f/16777216.f);
        float u3 = ((uint32_t)(r3 >> 40)) * (1.f/16777216.f);
        if (u0 * maxA <= a0) { f = f0; break; }
        if (u1 * maxA <= a1) { f = f1; break; }
        if (u2 * maxA <= a2) { f = f2; break; }
        if (u3 * maxA <= a3) { f = f3; break; }
        f = f3;   // fallback (practically unreachable)
    }
    // analytic face -> vertex indices (matches _grid_faces order)
    int i0, i1, i2;
    if (f < FH) {
        int c = f;  int i = c / 255, j = c - i*255;  int v = i*GSZ + j;
        i0 = v; i1 = v + 1; i2 = v + GSZ;                    // (v00, v01, v10)
    } else {
        int c = f - FH;  int i = c / 255, j = c - i*255;  int v = i*GSZ + j;
        i0 = v + 1; i1 = v + GSZ + 1; i2 = v + GSZ;          // (v01, v11, v10)
    }
    F3 v0 = ldv3(verts, i0), v1 = ldv3(verts, i1), v2 = ldv3(verts, i2);
    uint64_t r = splitmix64(st);
    float u0 = ((uint32_t)r >> 8) * (1.f/16777216.f);
    float u1 = ((uint32_t)(r >> 32) >> 8) * (1.f/16777216.f);
    float su = sqrtf(u0);
    float w0 = 1.f - su, w1 = su * (1.f - u1), w2 = su * u1;
    float X = w0*v0.x + w1*v1.x + w2*v2.x;
    float Y = w0*v0.y + w1*v1.y + w2*v2.y;
    float Z = w0*v0.z + w1*v1.z + w2*v2.z;
    samples[gid] = make_float4(X, Y, Z, X*X + Y*Y + Z*Z);
}

// ---------------------------------------------------------------------------
// k_heavy: fused chamfer partial-min (bx < 64 per b) + edge/normal/laplacian
// losses (bx >= 64). Chamfer: 4 src pts/thread x 64 blocks/mesh — NOT 8x32
// (round-8 lesson: fewer/longer blocks lengthen the kernel's critical path;
// LDS tile reads are broadcast and already free). FMA form:
//   |x-y|^2 = |x|^2 + (|y|^2 - 2 x.y)   -> 3 FMA + 1 min per pair.
// Mesh topology enumerated ANALYTICALLY (no index-array gathers).
__global__ void k_heavy(const float* __restrict__ vp,
                        const float4* __restrict__ samples,
                        int B, int E, int P, int nbE, int nbP,
                        float* __restrict__ minpart,
                        float* __restrict__ partE, float* __restrict__ partP,
                        float* __restrict__ partV) {
    int bx = blockIdx.x, b = blockIdx.y;
    if (bx < 64) {
        // ---- chamfer partial mins: xh = src half, q = dst chunk ----
        int xh = bx >> 5, z = bx & 31;
        int dir = z >> 4, q = z & 15;
        const float4* src = samples + ((size_t)dir*B + b)*NS;
        const float4* dst = samples + ((size_t)(1-dir)*B + b)*NS;

        __shared__ float4 tile[128];
        if (threadIdx.x < 128) tile[threadIdx.x] = dst[q*128 + threadIdx.x];

        float nx[4], ny[4], nz[4], xx[4], mn[4];
        #pragma unroll
        for (int k = 0; k < 4; ++k) {
            int i = xh*1024 + k*256 + threadIdx.x;
            float4 sp = src[i];
            nx[k] = -2.f*sp.x; ny[k] = -2.f*sp.y; nz[k] = -2.f*sp.z;
            xx[k] = sp.w;
            mn[k] = 3.402823466e38f;
        }
        __syncthreads();
        #pragma unroll 4
        for (int j = 0; j < 128; ++j) {
            float4 t = tile[j];
            #pragma unroll
            for (int k = 0; k < 4; ++k) {
                float d = fmaf(nx[k], t.x, t.w);
                d = fmaf(ny[k], t.y, d);
                d = fmaf(nz[k], t.z, d);
                mn[k] = fminf(mn[k], d);
            }
        }
        float* outp = minpart + (((size_t)(dir*B + b)*16) + q)*NS;
        #pragma unroll
        for (int k = 0; k < 4; ++k)
            outp[xh*1024 + k*256 + threadIdx.x] = mn[k] + xx[k];
        return;
    }

    // ---- mesh losses ----
    int mx = bx - 64;
    const float* verts = vp + (size_t)b*NV*3;
    float acc = 0.f;
    if (mx < nbE) {
        // edge loss, analytic 3-class enumeration
        int base = mx*(256*CH);
        for (int c = 0; c < CH; ++c) {
            int e = base + c*256 + threadIdx.x;
            if (e < E) {
                int i0, i1;
                if (e < EH) {                       // horizontal (r,c)-(r,c+1)
                    int r = e / 255, cc = e - r*255;
                    i0 = r*GSZ + cc; i1 = i0 + 1;
                } else if (e < EH + EV) {           // vertical (i,j)-(i+1,j)
                    int e2 = e - EH;
                    int i = e2 >> 8, j = e2 & 255;  // 255x256
                    i0 = i*GSZ + j; i1 = i0 + GSZ;
                } else {                            // diagonal (i,j+1)-(i+1,j)
                    int e2 = e - (EH + EV);
                    int i = e2 / 255, j = e2 - i*255;
                    i0 = i*GSZ + j + 1; i1 = (i+1)*GSZ + j;
                }
                F3 d = f3sub(ldv3(verts, i0), ldv3(verts, i1));
                acc += f3dot(d, d);
            }
        }
        float s = blockReduceSum256(acc);
        if (threadIdx.x == 0) partE[(size_t)mx*B + b] = s;
    } else if (mx < nbE + nbP) {
        // normal consistency, analytic 3-class enumeration of interior edges
        int base = (mx - nbE)*(256*CH);
        for (int c = 0; c < CH; ++c) {
            int p = base + c*256 + threadIdx.x;
            if (p < P) {
                int iv0, iv1, ia, ib;
                if (p < PH) {                       // horiz edge, r in [1,254]
                    int r = p / 255 + 1, cc = p - (r-1)*255;
                    iv0 = r*GSZ + cc; iv1 = iv0 + 1;
                    ia = iv0 + GSZ;                 // (r+1,c)
                    ib = iv0 - GSZ + 1;             // (r-1,c+1)
                } else if (p < PH + PV) {           // vert edge, j in [1,254]
                    int p2 = p - PH;
                    int r = p2 / 254, j = p2 - r*254 + 1;
                    iv0 = r*GSZ + j; iv1 = iv0 + GSZ;
                    ia = iv0 + 1;                   // (r,j+1)
                    ib = iv0 + GSZ - 1;             // (r+1,j-1)
                } else {                            // diagonal edge of cell (i,j)
                    int p2 = p - (PH + PV);
                    int i = p2 / 255, j = p2 - i*255;
                    iv0 = i*GSZ + j + 1;            // (i,j+1)
                    iv1 = (i+1)*GSZ + j;            // (i+1,j)
                    ia = i*GSZ + j;                 // (i,j)
                    ib = (i+1)*GSZ + j + 1;         // (i+1,j+1)
                }
                F3 v0 = ldv3(verts, iv0), v1 = ldv3(verts, iv1);
                F3 a = ldv3(verts, ia), bb = ldv3(verts, ib);
                F3 e = f3sub(v1, v0);
                F3 n0 = f3cross(e, f3sub(a, v0));
                F3 n1 = f3cross(f3sub(bb, v0), e);     // == -cross(e, bb-v0)
                float num = f3dot(n0, n1);
                float den2 = fmaxf(f3dot(n0, n0), 1e-16f) * fmaxf(f3dot(n1, n1), 1e-16f);
                acc += 1.f - num * rsqrtf(den2);
            }
        }
        float s = blockReduceSum256(acc);
        if (threadIdx.x == 0) partP[(size_t)(mx - nbE)*B + b] = s;
    } else {
        int base = (mx - nbE - nbP)*(256*CH);
        for (int c = 0; c < CH; ++c) {
            int idx = base + c*256 + threadIdx.x;      // < NV always (nbV exact)
            int i = idx >> 8, j = idx & 255;
            F3 ctr = ldv3(verts, idx);
            float nx = 0.f, ny = 0.f, nz = 0.f; int deg = 0;
            #define ADDN(ii, jj) { F3 n_ = ldv3(verts, (ii)*GSZ + (jj)); \
                                   nx += n_.x; ny += n_.y; nz += n_.z; ++deg; }
            if (j > 0)               ADDN(i, j-1);
            if (j < GSZ-1)           ADDN(i, j+1);
            if (i > 0)               ADDN(i-1, j);
            if (i < GSZ-1)           ADDN(i+1, j);
            if (i < GSZ-1 && j > 0)  ADDN(i+1, j-1);   // anti-diagonal
            if (i > 0 && j < GSZ-1)  ADDN(i-1, j+1);
            #undef ADDN
            float inv = 1.f / (float)deg;
            float lx = nx*inv - ctr.x, ly = ny*inv - ctr.y, lz = nz*inv - ctr.z;
            acc += sqrtf(lx*lx + ly*ly + lz*lz);
        }
        float s = blockReduceSum256(acc);
        if (threadIdx.x == 0) partV[(size_t)(mx - nbE - nbP)*B + b] = s;
    }
}

// ---------------------------------------------------------------------------
// k_redfin: combine 16 dst-chunk partial mins per src point, block partial
// sums; the LAST block (atomic counter: only 128 same-address adds + 128
// fences — cheap at this scale) does the fp64 finish and writes 5 outputs.
// grid: (2*B*NS)/256 = 128 blocks
__global__ void k_redfin(const float* __restrict__ minpart, int B,
                         const float* __restrict__ partE, int nE,
                         const float* __restrict__ partP, int nP,
                         const float* __restrict__ partV, int nL,
                         int E, int P,
                         float* __restrict__ chamPart,
                         unsigned* __restrict__ counter,
                         float* __restrict__ out) {
    int gid = blockIdx.x*256 + threadIdx.x;
    int dir = gid / (B*NS);
    int rem = gid - dir*(B*NS);
    int b = rem / NS, i = rem - b*NS;
    const float* p = minpart + (size_t)(dir*B + b)*16*NS + i;
    float mn = 3.402823466e38f;
    #pragma unroll
    for (int q = 0; q < 16; ++q) mn = fminf(mn, p[(size_t)q*NS]);
    float sm = blockReduceSum256(mn);
    if (threadIdx.x == 0) chamPart[blockIdx.x] = sm;   // blocks 0..63 dir0, 64..127 dir1

    // last-block-done detection
    __shared__ unsigned sTicket;
    if (threadIdx.x == 0) {
        __threadfence();
        sTicket = atomicAdd(counter, 1u);
    }
    __syncthreads();
    if (sTicket != (unsigned)(gridDim.x - 1)) return;
    __threadfence();

    // ---- final fp64 accumulation (single surviving block) ----
    const volatile float* cp = chamPart;               // peer-block results
    double a0 = 0, a1 = 0, aE = 0, aP = 0, aL = 0;
    for (int k = threadIdx.x; k < 64;  k += 256) a0 += (double)cp[k];
    for (int k = 64 + threadIdx.x; k < 128; k += 256) a1 += (double)cp[k];
    for (int k = threadIdx.x; k < nE; k += 256) aE += (double)partE[k];
    for (int k = threadIdx.x; k < nP; k += 256) aP += (double)partP[k];
    for (int k = threadIdx.x; k < nL; k += 256) aL += (double)partV[k];
    __shared__ double sd[5][4];
    double v[5] = {a0, a1, aE, aP, aL};
    int lane = threadIdx.x & 63, w = threadIdx.x >> 6;
    #pragma unroll
    for (int r = 0; r < 5; ++r) {
        double x = v[r];
        #pragma unroll
        for (int o = 32; o > 0; o >>= 1) x += __shfl_down(x, o, 64);
        if (lane == 0) sd[r][w] = x;
    }
    __syncthreads();
    if (threadIdx.x == 0) {
        double bn = (double)B * NS;
        double ch = (sd[0][0]+sd[0][1]+sd[0][2]+sd[0][3]) / bn
                  + (sd[1][0]+sd[1][1]+sd[1][2]+sd[1][3]) / bn;
        double ed = (sd[2][0]+sd[2][1]+sd[2][2]+sd[2][3]) / ((double)B * E);
        double no = (sd[3][0]+sd[3][1]+sd[3][2]+sd[3][3]) / ((double)B * P);
        double la = (sd[4][0]+sd[4][1]+sd[4][2]+sd[4][3]) / ((double)B * NV);
        double loss = ch + ed + 0.1*no + 0.1*la;
        out[0] = (float)loss; out[1] = (float)ch; out[2] = (float)ed;
        out[3] = (float)no;   out[4] = (float)la;
    }
}

extern "C" void kernel_launch(void* const* d_in, const int* in_sizes, int n_in,
                              void* d_out, int out_size, void* d_ws, size_t ws_size,
                              hipStream_t stream) {
    const float* vp = (const float*)d_in[0];
    const float* vt = (const float*)d_in[1];
    const int B = in_sizes[0] / (3*NV);
    const int E = in_sizes[3] / 2;   // 195585 (denominator; topology is analytic)
    const int P = in_sizes[4] / 4;   // 194565

    char* ws = (char*)d_ws;
    size_t off = 0;
    auto alloc = [&](size_t bytes) -> void* {
        void* p = ws + off;
        off = (off + bytes + 255) & ~(size_t)255;
        return p;
    };
    float*    areas    = (float*)   alloc((size_t)2*B*NF*sizeof(float));      // 8.3 MB
    float4*   samples  = (float4*)  alloc((size_t)2*B*NS*sizeof(float4));     // 1.0 MB
    float*    minpart  = (float*)   alloc((size_t)2*B*16*NS*sizeof(float));   // 2.1 MB
    float*    blockmax = (float*)   alloc(8192*sizeof(float));
    float*    chamPart = (float*)   alloc(256*sizeof(float));
    float*    partE    = (float*)   alloc(2048*sizeof(float));
    float*    partP    = (float*)   alloc(2048*sizeof(float));
    float*    partV    = (float*)   alloc(1024*sizeof(float));
    unsigned* counter  = (unsigned*)alloc(256);

    int nbm = (2*B*CELLS + 255)/256;                    // k_area blocks (4065)
    k_area<<<nbm, 256, 0, stream>>>(vp, vt, B, areas, blockmax, counter);
    k_sample<<<(2*B*NS)/256, 256, 0, stream>>>(vp, vt, B, areas, blockmax, nbm, samples);
    int nbE = (E + 256*CH - 1)/(256*CH);
    int nbP = (P + 256*CH - 1)/(256*CH);
    int nbV = NV/(256*CH);
    dim3 gh(64 + nbE + nbP + nbV, B);
    k_heavy<<<gh, 256, 0, stream>>>(vp, samples, B, E, P, nbE, nbP,
                                    minpart, partE, partP, partV);
    k_redfin<<<(2*B*NS)/256, 256, 0, stream>>>(minpart, B, partE, nbE*B,
                                               partP, nbP*B, partV, nbV*B,
                                               E, P, chamPart, counter,
                                               (float*)d_out);
}